// Round 9
// baseline (650.739 us; speedup 1.0000x reference)
//
#include <hip/hip_runtime.h>
#include <hip/hip_bf16.h>

typedef __hip_bfloat16 bf16_t;
typedef __bf16 bf16x8 __attribute__((ext_vector_type(8)));
typedef float floatx4 __attribute__((ext_vector_type(4)));

#define DEVINL __device__ __forceinline__

DEVINL floatx4 mfma16(bf16x8 a, bf16x8 b, floatx4 c) {
  return __builtin_amdgcn_mfma_f32_16x16x32_bf16(a, b, c, 0, 0, 0);
}

// async global->LDS, 16B per lane, lane l lands at lds_base + l*16
DEVINL void gload_lds16(const bf16_t* gp, bf16_t* lp) {
  __builtin_amdgcn_global_load_lds(
      (const __attribute__((address_space(1))) unsigned int*)gp,
      (__attribute__((address_space(3))) unsigned int*)lp, 16, 0, 0);
}

template <class CT> DEVINL CT cvtC(float f);
template <> DEVINL bf16_t cvtC<bf16_t>(float f) { return __float2bfloat16(f); }
template <> DEVINL float cvtC<float>(float f) { return f; }

DEVINL unsigned int pack_bf2(float a, float b) {
  union { bf16_t h; unsigned short s; } ua, ub;
  ua.h = __float2bfloat16(a);
  ub.h = __float2bfloat16(b);
  return (unsigned int)ua.s | ((unsigned int)ub.s << 16);
}

// ---------------------------------------------------------------------------
// xbf[i] = bf16(x[i]); n must be multiple of 2048. 8 elems/thread.
// ---------------------------------------------------------------------------
__global__ void convert_f32_bf16(const float* __restrict__ in,
                                 bf16_t* __restrict__ out) {
  size_t i = ((size_t)blockIdx.x * 256 + threadIdx.x) * 8;
  floatx4 a = *(const floatx4*)(in + i);
  floatx4 b = *(const floatx4*)(in + i + 4);
  bf16x8 r;
#pragma unroll
  for (int j = 0; j < 4; j++) r[j] = (__bf16)a[j];
#pragma unroll
  for (int j = 0; j < 4; j++) r[4 + j] = (__bf16)b[j];
  *(bf16x8*)(out + i) = r;
}

// ---------------------------------------------------------------------------
// C[M,N] = A[M,K] @ BT[N,K]^T  (A,BT bf16; C bf16 or fp32).
// TMxTN tile, BK=64, 4 waves in 2x2, register-prefetch pipeline, single LDS
// buffer [(TM+TN)/16 subtiles][kc2][512]. Smaller tiles than 128x128 —
// both GEMMs were latency-bound at 2-2.4 resident blocks/CU (MfmaUtil 21%,
// VALU 8%, HBM 26%): more blocks/CU is the one untried axis.
// SPLITV (TN=128 only): col0>=4096 tiles written transposed to VT[b,h,d,s].
// ---------------------------------------------------------------------------
template <int TM, int TN, bool SPLITV, class CT>
__global__ __launch_bounds__(256, 4) void gemm_bt(
    const bf16_t* __restrict__ A, const bf16_t* __restrict__ BT,
    CT* __restrict__ C, bf16_t* __restrict__ VTout, int N, int CN, int K) {
  constexpr int NST = (TM + TN) / 16;  // 16-row subtiles (A then B)
  constexpr int PW = NST / 4;          // subtiles staged per wave
  constexpr int FM = TM / 32, FN = TN / 32;  // frags per wave
  __shared__ __align__(16) bf16_t lds[NST * 1024];

  const int tid = threadIdx.x;
  const int wave = tid >> 6;
  const int lane = tid & 63;
  const int quad = lane >> 4;
  const int l16 = lane & 15;
  const int wm = wave >> 1, wn = wave & 1;

  const int nx = N / TN;
  const int bid = blockIdx.x;
  const int col0 = (bid % nx) * TN;
  const int row0 = (bid / nx) * TM;

  // global base pointers for this wave's PW subtiles
  const bf16_t* gb[PW];
#pragma unroll
  for (int t = 0; t < PW; t++) {
    int st = wave * PW + t;
    gb[t] = (st < TM / 16)
                ? A + (size_t)(row0 + st * 16 + l16) * K + quad * 8
                : BT + (size_t)(col0 + (st - TM / 16) * 16 + l16) * K + quad * 8;
  }

  bf16x8 pr[PW][2];
  auto load_tile = [&](int k0) {
#pragma unroll
    for (int t = 0; t < PW; t++)
#pragma unroll
      for (int kc = 0; kc < 2; kc++)
        pr[t][kc] = *(const bf16x8*)(gb[t] + k0 + kc * 32);
  };
  auto store_tile = [&]() {
#pragma unroll
    for (int t = 0; t < PW; t++)
#pragma unroll
      for (int kc = 0; kc < 2; kc++)
        *(bf16x8*)(lds + (wave * PW + t) * 1024 + kc * 512 + lane * 8) =
            pr[t][kc];
  };

  load_tile(0);
  store_tile();
  __syncthreads();

  floatx4 acc[FM][FN] = {};
  for (int k0 = 0; k0 < K; k0 += 64) {
    const bool more = (k0 + 64) < K;
    if (more) load_tile(k0 + 64);  // prefetch ahead of the MFMA block
#pragma unroll
    for (int kc = 0; kc < 2; kc++) {
      bf16x8 af[FM], bfr[FN];
#pragma unroll
      for (int i = 0; i < FM; i++)
        af[i] = *(const bf16x8*)(lds + (wm * FM + i) * 1024 + kc * 512 +
                                 lane * 8);
#pragma unroll
      for (int j = 0; j < FN; j++)
        bfr[j] = *(const bf16x8*)(lds + (TM / 16 + wn * FN + j) * 1024 +
                                  kc * 512 + lane * 8);
#pragma unroll
      for (int i = 0; i < FM; i++)
#pragma unroll
        for (int j = 0; j < FN; j++)
          acc[i][j] = mfma16(af[i], bfr[j], acc[i][j]);
    }
    __syncthreads();  // all LDS reads of tile k done
    if (more) store_tile();
    __syncthreads();  // tile k+1 visible
  }

  if (!SPLITV || col0 < 4096) {
#pragma unroll
    for (int i = 0; i < FM; i++)
#pragma unroll
      for (int j = 0; j < FN; j++)
#pragma unroll
        for (int r = 0; r < 4; r++) {
          int row = row0 + wm * (TM / 2) + i * 16 + quad * 4 + r;
          int col = col0 + wn * (TN / 2) + j * 16 + l16;
          C[(size_t)row * CN + col] = cvtC<CT>(acc[i][j][r]);
        }
  } else {
    // v-tile -> VT[b,h,d,s]; 4 consecutive s per floatx4 = 8B stores
    const int h = (col0 - 4096) >> 7;
    const int b = row0 >> 11;
    const int s0 = row0 & 2047;
    bf16_t* vt = VTout + (size_t)(b * 16 + h) * 128 * 2048;
    struct __align__(8) bf4 { bf16_t v[4]; };
#pragma unroll
    for (int i = 0; i < FM; i++)
#pragma unroll
      for (int j = 0; j < FN; j++) {
        int d = wn * (TN / 2) + j * 16 + l16;
        int s = s0 + wm * (TM / 2) + i * 16 + quad * 4;
        bf4 o;
#pragma unroll
        for (int r = 0; r < 4; r++) o.v[r] = __float2bfloat16(acc[i][j][r]);
        *(bf4*)(vt + (size_t)d * 2048 + s) = o;
      }
  }
}

// ---------------------------------------------------------------------------
// out[N][M] = bf16(in[M][N]^T), in fp32, 32x32 LDS tiles
// ---------------------------------------------------------------------------
__global__ void transposecvt(const float* __restrict__ in,
                             bf16_t* __restrict__ out, int M, int N) {
  __shared__ bf16_t tile[32][33];
  int n0 = blockIdx.x * 32, m0 = blockIdx.y * 32;
  tile[threadIdx.y][threadIdx.x] =
      __float2bfloat16(in[(size_t)(m0 + threadIdx.y) * N + n0 + threadIdx.x]);
  __syncthreads();
  out[(size_t)(n0 + threadIdx.y) * M + m0 + threadIdx.x] =
      tile[threadIdx.x][threadIdx.y];
}

// ---------------------------------------------------------------------------
// RoPE on q,k IN-PLACE in qkv2 [B,S,2,H,hd]; q additionally scaled hd^-0.5.
// ---------------------------------------------------------------------------
__global__ void rope_qk(bf16_t* __restrict__ qkv) {
  struct __align__(8) bf4 { bf16_t v[4]; };
  int t = blockIdx.x * 256 + threadIdx.x;
  int dc = t & 15;
  int s = (t >> 4) & 2047;
  int h = (t >> 15) & 15;
  int b = t >> 19;
  int d = dc * 4;
  size_t base = ((size_t)(b * 2048 + s) * 2) * 2048 + h * 128;
  bf4 ql = *(const bf4*)(qkv + base + d);
  bf4 qh = *(const bf4*)(qkv + base + d + 64);
  bf4 kl = *(const bf4*)(qkv + base + 2048 + d);
  bf4 kh = *(const bf4*)(qkv + base + 2048 + d + 64);
  bf4 oql, oqh, okl, okh;
  const float scale = 0.08838834764831845f;  // 1/sqrt(128)
#pragma unroll
  for (int i = 0; i < 4; i++) {
    int j = d + i;
    float fr = (float)s * powf(10000.0f, -(float)j * (1.0f / 64.0f));
    float c = cosf(fr);
    float sn = sinf(fr);
    float qlo = __bfloat162float(ql.v[i]), qhi = __bfloat162float(qh.v[i]);
    float klo = __bfloat162float(kl.v[i]), khi = __bfloat162float(kh.v[i]);
    oql.v[i] = __float2bfloat16((qlo * c - qhi * sn) * scale);
    oqh.v[i] = __float2bfloat16((qhi * c + qlo * sn) * scale);
    okl.v[i] = __float2bfloat16(klo * c - khi * sn);
    okh.v[i] = __float2bfloat16(khi * c + klo * sn);
  }
  *(bf4*)(qkv + base + d) = oql;
  *(bf4*)(qkv + base + d + 64) = oqh;
  *(bf4*)(qkv + base + 2048 + d) = okl;
  *(bf4*)(qkv + base + 2048 + d + 64) = okh;
}

// ---------------------------------------------------------------------------
// Flash attention v4 (non-causal, unstabilized softmax — |scores| <~6).
// Grid (S/128, B*H) = 512 blocks, 256 threads, 128 q-rows/block (32/wave).
// Q,K from qkv2 (stride 4096), V^T from VT. K/V^T tiles staged cooperatively
// via global_load_lds; S^T = K·Q^T, O^T = V^T·P^T with in-register P^T frags.
// ---------------------------------------------------------------------------
__global__ __launch_bounds__(256, 2) void flash_attn(
    const bf16_t* __restrict__ qkv, const bf16_t* __restrict__ VT,
    bf16_t* __restrict__ Out) {
  const int S = 2048;
  const int RS = 4096;  // qkv2 row stride
  const int tid = threadIdx.x;
  const int wave = tid >> 6;
  const int lane = tid & 63;
  const int quad = lane >> 4;
  const int l16 = lane & 15;

  const int bh = blockIdx.y;
  const int q0 = blockIdx.x * 128;
  const int b = bh >> 4, h = bh & 15;

  const bf16_t* Qb = qkv + (size_t)b * S * RS + h * 128;
  const bf16_t* Kb = Qb + 2048;
  const bf16_t* Vb = VT + (size_t)bh * 128 * S;

  __shared__ __align__(16) bf16_t k_lds[16384];  // 32 KB
  __shared__ __align__(16) bf16_t v_lds[16384];  // 32 KB

  bf16x8 qf[2][4];
#pragma unroll
  for (int qn = 0; qn < 2; qn++)
#pragma unroll
    for (int ks = 0; ks < 4; ks++)
      qf[qn][ks] = *(const bf16x8*)(
          Qb + (size_t)(q0 + wave * 32 + qn * 16 + l16) * RS + ks * 32 +
          quad * 8);

  floatx4 o_acc[2][8] = {};
  float l_part[2] = {0.f, 0.f};

  const int sA = l16 + 32 * (quad & 1);
  const int sB = sA + 16;
  const bool hi = quad >= 2;

  for (int kt = 0; kt < S / 128; kt++) {
    const int kk0 = kt * 128;
#pragma unroll
    for (int t = 0; t < 2; t++) {
      int mt = wave * 2 + t;
#pragma unroll
      for (int ks = 0; ks < 4; ks++) {
        gload_lds16(Kb + (size_t)(kk0 + mt * 16 + l16) * RS + ks * 32 + quad * 8,
                    k_lds + mt * 2048 + ks * 512);
        gload_lds16(Vb + (size_t)(mt * 16 + l16) * S + kk0 + ks * 32 + quad * 8,
                    v_lds + mt * 2048 + ks * 512);
      }
    }
    __syncthreads();

    floatx4 s_acc[2][8] = {};
#pragma unroll
    for (int ks = 0; ks < 4; ks++)
#pragma unroll
      for (int mt = 0; mt < 8; mt++) {
        bf16x8 kf = *(const bf16x8*)(k_lds + mt * 2048 + ks * 512 + lane * 8);
        s_acc[0][mt] = mfma16(kf, qf[0][ks], s_acc[0][mt]);
        s_acc[1][mt] = mfma16(kf, qf[1][ks], s_acc[1][mt]);
      }

    unsigned int p01[2][8], p23[2][8];
#pragma unroll
    for (int qn = 0; qn < 2; qn++)
#pragma unroll
      for (int mt = 0; mt < 8; mt++) {
        float e0 = __expf(s_acc[qn][mt][0]);
        float e1 = __expf(s_acc[qn][mt][1]);
        float e2 = __expf(s_acc[qn][mt][2]);
        float e3 = __expf(s_acc[qn][mt][3]);
        l_part[qn] += (e0 + e1) + (e2 + e3);
        p01[qn][mt] = pack_bf2(e0, e1);
        p23[qn][mt] = pack_bf2(e2, e3);
      }

#pragma unroll
    for (int kc = 0; kc < 4; kc++) {
#pragma unroll
      for (int qn = 0; qn < 2; qn++) {
        unsigned int a0 = __shfl(p01[qn][2 * kc], sA);
        unsigned int b0 = __shfl(p01[qn][2 * kc + 1], sA);
        unsigned int a1 = __shfl(p23[qn][2 * kc], sA);
        unsigned int b1 = __shfl(p23[qn][2 * kc + 1], sA);
        unsigned int a2 = __shfl(p01[qn][2 * kc], sB);
        unsigned int b2 = __shfl(p01[qn][2 * kc + 1], sB);
        unsigned int a3 = __shfl(p23[qn][2 * kc], sB);
        unsigned int b3 = __shfl(p23[qn][2 * kc + 1], sB);
        union { unsigned int u[4]; bf16x8 v; } bp;
        bp.u[0] = hi ? b0 : a0;
        bp.u[1] = hi ? b1 : a1;
        bp.u[2] = hi ? b2 : a2;
        bp.u[3] = hi ? b3 : a3;
#pragma unroll
        for (int dt = 0; dt < 8; dt++) {
          bf16x8 vf = *(const bf16x8*)(v_lds + dt * 2048 + kc * 512 + lane * 8);
          o_acc[qn][dt] = mfma16(vf, bp.v, o_acc[qn][dt]);
        }
      }
    }
    __syncthreads();
  }

#pragma unroll
  for (int qn = 0; qn < 2; qn++) {
    l_part[qn] += __shfl_xor(l_part[qn], 16);
    l_part[qn] += __shfl_xor(l_part[qn], 32);
  }

  struct __align__(8) bf4 { bf16_t v[4]; };
#pragma unroll
  for (int qn = 0; qn < 2; qn++) {
    float inv = 1.f / l_part[qn];
    size_t s = q0 + wave * 32 + qn * 16 + l16;
#pragma unroll
    for (int dt = 0; dt < 8; dt++) {
      bf4 o;
#pragma unroll
      for (int r = 0; r < 4; r++)
        o.v[r] = __float2bfloat16(o_acc[qn][dt][r] * inv);
      *(bf4*)(Out + ((size_t)b * S + s) * 2048 + h * 128 + dt * 16 + quad * 4) = o;
    }
  }
}

// ---------------------------------------------------------------------------
extern "C" void kernel_launch(void* const* d_in, const int* in_sizes, int n_in,
                              void* d_out, int out_size, void* d_ws,
                              size_t ws_size, hipStream_t stream) {
  const float* x = (const float*)d_in[0];
  const float* w_qkv = (const float*)d_in[1];
  const float* w_out = (const float*)d_in[2];
  float* out = (float*)d_out;
  char* ws = (char*)d_ws;

  const int B = 2, S = 2048, D = 2048;
  // ws layout (total 92.3 MB, all bf16):
  //   [0, 33.5MB)     qkv2 [B,S,2,H,hd] (q,k only) — dead after flash -> woutT
  //   [33.5, 58.7MB)  wqkvT — dead after QKV GEMM -> attn
  //   [58.7, 75.5MB)  xbf — dead after QKV GEMM
  //   [75.5, 92.3MB)  VT [B,H,hd,S] (written by QKV GEMM epilogue)
  bf16_t* qkv2 = (bf16_t*)(ws);
  bf16_t* wqkvT = (bf16_t*)(ws + (size_t)B * S * 2 * D * 2);
  bf16_t* xbf = (bf16_t*)(ws + (size_t)B * S * 2 * D * 2 + (size_t)3 * D * D * 2);
  bf16_t* VT = (bf16_t*)(ws + (size_t)B * S * 2 * D * 2 + (size_t)3 * D * D * 2 +
                         (size_t)B * S * D * 2);
  bf16_t* attn = wqkvT;   // dead after QKV GEMM
  bf16_t* woutT = qkv2;   // dead after flash

  dim3 b32(32, 32);
  convert_f32_bf16<<<(B * S * D) / 2048, 256, 0, stream>>>(x, xbf);
  transposecvt<<<dim3(3 * D / 32, D / 32), b32, 0, stream>>>(w_qkv, wqkvT, D, 3 * D);
  gemm_bt<64, 128, true, bf16_t>
      <<<(B * S / 64) * (3 * D / 128), 256, 0, stream>>>(
          xbf, wqkvT, qkv2, VT, 3 * D, 2 * D, D);
  rope_qk<<<4096, 256, 0, stream>>>(qkv2);
  flash_attn<<<dim3(S / 128, B * 16), 256, 0, stream>>>(qkv2, VT, attn);
  transposecvt<<<dim3(D / 32, D / 32), b32, 0, stream>>>(w_out, woutT, D, D);
  gemm_bt<64, 64, false, float>
      <<<(B * S / 64) * (D / 64), 256, 0, stream>>>(
          attn, woutT, out, nullptr, D, D, D);
}